// Round 6
// baseline (333.094 us; speedup 1.0000x reference)
//
#include <hip/hip_runtime.h>
#include <stdint.h>

// WhaleAttention: B=2 N=2048 C=1024 H=16 D=64
// R4 re-resubmit (2x infra failure, error precedes source push): T3-min 2-phase pipelining.
//  - flash: double-buffered K/V LDS (112KB), stage(t+1) issued BEFORE compute(t),
//    one barrier/tile (vmcnt drain covered by ~2000cy compute). exp2-domain softmax.
//  - GEMMs: global_load_lds staging + double-buffered LDS (issue-ahead).

typedef short short8 __attribute__((ext_vector_type(8)));
typedef float f32x4 __attribute__((ext_vector_type(4)));
typedef unsigned short us4 __attribute__((ext_vector_type(4)));
typedef unsigned short u16;

#define NB 2
#define NN 2048
#define NC 1024
#define NH 16
#define ND 64

__device__ __forceinline__ u16 f2bf(float f) {
    unsigned int u = __float_as_uint(f);
    u += 0x7fffu + ((u >> 16) & 1u);
    return (u16)(u >> 16);
}

// swizzled column for a 128-u16 row: permute 16B chunks by XOR(row&7). involution.
__device__ __forceinline__ int swzc(int row, int c) {
    return (((c >> 3) ^ (row & 7)) << 3) | (c & 7);
}

__device__ __forceinline__ void gload16(const void* g, void* l) {
    __builtin_amdgcn_global_load_lds(
        (const __attribute__((address_space(1))) unsigned int*)g,
        (__attribute__((address_space(3))) unsigned int*)l, 16, 0, 0);
}

// ---------------- cast fp32 -> bf16 ----------------
__global__ __launch_bounds__(256) void cast_kernel(const float* __restrict__ src,
                                                   u16* __restrict__ dst, int n4) {
    int i = blockIdx.x * 256 + threadIdx.x;
    if (i < n4) {
        float4 f = reinterpret_cast<const float4*>(src)[i];
        us4 o;
        o[0] = f2bf(f.x); o[1] = f2bf(f.y); o[2] = f2bf(f.z); o[3] = f2bf(f.w);
        reinterpret_cast<us4*>(dst)[i] = o;
    }
}

// ---------------- GEMM C = A @ W^T (+bias), out fp32; gload_lds + dbuf ----------------
__device__ __forceinline__ void gemm_stage(const u16* __restrict__ A,
                                           const u16* __restrict__ W,
                                           u16* As, u16* Bs,
                                           int m0, int n0, int kk, int w, int lane) {
    int lr4 = lane >> 2, lc8 = (lane & 3) * 8;
#pragma unroll
    for (int i = 0; i < 2; i++) {
        int rbase = w * 32 + i * 16;
        gload16(A + (size_t)(m0 + rbase + lr4) * 1024 + kk + lc8, As + rbase * 32);
        gload16(W + (size_t)(n0 + rbase + lr4) * 1024 + kk + lc8, Bs + rbase * 32);
    }
}

__device__ __forceinline__ void gemm_bt_body(const u16* __restrict__ A,
                                             const u16* __restrict__ W,
                                             float* __restrict__ out,
                                             const float* __restrict__ bias,
                                             int m0, int n0) {
    __shared__ u16 As[2][128 * 32];
    __shared__ u16 Bs[2][128 * 32];
    int t = threadIdx.x, lane = t & 63, w = t >> 6;
    int wm = (w >> 1) * 64, wn = (w & 1) * 64;
    int lr = lane & 15, lg = lane >> 4;
    f32x4 acc[4][4] = {};

    gemm_stage(A, W, As[0], Bs[0], m0, n0, 0, w, lane);
    __syncthreads();
    int cur = 0;
    for (int kt = 0; kt < 32; kt++) {
        if (kt < 31)
            gemm_stage(A, W, As[cur ^ 1], Bs[cur ^ 1], m0, n0, (kt + 1) * 32, w, lane);
        const u16* Ac = As[cur];
        const u16* Bc = Bs[cur];
        short8 af[4], bw[4];
#pragma unroll
        for (int mt = 0; mt < 4; mt++)
            af[mt] = *reinterpret_cast<const short8*>(Ac + (wm + mt * 16 + lr) * 32 + lg * 8);
#pragma unroll
        for (int nt = 0; nt < 4; nt++)
            bw[nt] = *reinterpret_cast<const short8*>(Bc + (wn + nt * 16 + lr) * 32 + lg * 8);
#pragma unroll
        for (int mt = 0; mt < 4; mt++)
#pragma unroll
            for (int nt = 0; nt < 4; nt++)
                acc[mt][nt] = __builtin_amdgcn_mfma_f32_16x16x32_bf16(af[mt], bw[nt], acc[mt][nt], 0, 0, 0);
        __syncthreads();
        cur ^= 1;
    }
#pragma unroll
    for (int mt = 0; mt < 4; mt++) {
#pragma unroll
        for (int nt = 0; nt < 4; nt++) {
            int c = n0 + wn + nt * 16 + lr;
            float badd = bias ? bias[c] : 0.0f;
            int r = m0 + wm + mt * 16 + lg * 4;
#pragma unroll
            for (int rg = 0; rg < 4; rg++)
                out[(size_t)(r + rg) * 1024 + c] = acc[mt][nt][rg] + badd;
        }
    }
}

// z=0:q(bq) 1:k(bk) 2:v(bv) 3:p(none, A=pos)
__global__ __launch_bounds__(256) void proj_gemm(const u16* __restrict__ xbf,
                                                 const u16* __restrict__ posbf,
                                                 const u16* __restrict__ Wbase,
                                                 float* __restrict__ prebase,
                                                 const float* __restrict__ bq,
                                                 const float* __restrict__ bk,
                                                 const float* __restrict__ bv) {
    int z = blockIdx.z;
    const u16* A = (z == 3) ? posbf : xbf;
    const u16* W = Wbase + (size_t)z * 1048576;
    float* out = prebase + (size_t)z * 4194304;
    const float* bias = (z == 0) ? bq : ((z == 1) ? bk : ((z == 2) ? bv : (const float*)nullptr));
    gemm_bt_body(A, W, out, bias, blockIdx.y * 128, blockIdx.x * 128);
}

__global__ __launch_bounds__(256) void out_gemm(const u16* __restrict__ ctx,
                                                const u16* __restrict__ Wo,
                                                float* __restrict__ out,
                                                const float* __restrict__ bo) {
    gemm_bt_body(ctx, Wo, out, bo, blockIdx.y * 128, blockIdx.x * 128);
}

// ---------------- LN on q/k rows; QQ=[s*(q^+u) | s*(q^+v)], KK[:,0:64]=k^  (pre-swizzled)
//   s = 0.125 * log2(e)  (softmax runs in exp2 domain) ----------------
__global__ __launch_bounds__(256) void post_qk(const float* __restrict__ prebase,
                                               const float* __restrict__ qw, const float* __restrict__ qb,
                                               const float* __restrict__ kw, const float* __restrict__ kb,
                                               const float* __restrict__ pbu, const float* __restrict__ pbv,
                                               u16* __restrict__ QQ, u16* __restrict__ KK) {
    const float QSC = 0.125f * 1.44269504089f;
    int isq = (blockIdx.y == 0);
    const float* pre = prebase + (isq ? 0 : (size_t)4194304);
    const float* lw = isq ? qw : kw;
    const float* lb = isq ? qb : kb;
    int wv = threadIdx.x >> 6, lane = threadIdx.x & 63;
    int row = blockIdx.x * 4 + wv;   // 0..4095
    int b = row >> 11, n = row & 2047;
    const float* pr = pre + (size_t)row * 1024;
    float vals[16];
    float s = 0.f, s2 = 0.f;
#pragma unroll
    for (int i = 0; i < 4; i++) {
        float4 f = *reinterpret_cast<const float4*>(pr + i * 256 + lane * 4);
        vals[i * 4 + 0] = f.x; vals[i * 4 + 1] = f.y; vals[i * 4 + 2] = f.z; vals[i * 4 + 3] = f.w;
        s += f.x + f.y + f.z + f.w;
        s2 += f.x * f.x + f.y * f.y + f.z * f.z + f.w * f.w;
    }
#pragma unroll
    for (int m = 1; m < 64; m <<= 1) { s += __shfl_xor(s, m); s2 += __shfl_xor(s2, m); }
    float mean = s * (1.f / 1024.f);
    float var = s2 * (1.f / 1024.f) - mean * mean;
    float inv = rsqrtf(var + 1e-6f);
#pragma unroll
    for (int i = 0; i < 4; i++) {
        int c0 = i * 256 + lane * 4;
        int h = c0 >> 6, d0 = c0 & 63;
        size_t base = ((size_t)(b * NH + h) * NN + n) * 128;
        if (isq) {
            us4 u0, u1;
#pragma unroll
            for (int j = 0; j < 4; j++) {
                float xn = (vals[i * 4 + j] - mean) * inv * lw[c0 + j] + lb[c0 + j];
                u0[j] = f2bf((xn + pbu[h * 64 + d0 + j]) * QSC);
                u1[j] = f2bf((xn + pbv[h * 64 + d0 + j]) * QSC);
            }
            *reinterpret_cast<us4*>(QQ + base + swzc(n, d0)) = u0;
            *reinterpret_cast<us4*>(QQ + base + swzc(n, d0 + 64)) = u1;
        } else {
            us4 u0;
#pragma unroll
            for (int j = 0; j < 4; j++) {
                float xn = (vals[i * 4 + j] - mean) * inv * lw[c0 + j] + lb[c0 + j];
                u0[j] = f2bf(xn);
            }
            *reinterpret_cast<us4*>(KK + base + swzc(n, d0)) = u0;
        }
    }
}

// ---------------- v -> Vt[b][h][d][n] (pre-swizzled by d), p -> KK[:,64:128] (pre-swizzled by n) ----------------
__global__ __launch_bounds__(256) void post_vp(const float* __restrict__ vpre,
                                               const float* __restrict__ ppre,
                                               u16* __restrict__ Vt, u16* __restrict__ KK) {
    __shared__ u16 tile[64][66];
    int bh = blockIdx.x;               // 0..31
    int b = bh >> 4, h = bh & 15;
    int n0 = blockIdx.y * 64;
    int t = threadIdx.x, lane = t & 63, w = t >> 6;
#pragma unroll
    for (int j = 0; j < 4; j++) {
        int nr = t >> 2;                 // 0..63
        int d = (t & 3) * 16 + j * 4;    // 0..63
        int n = n0 + nr;
        size_t goff = ((size_t)(b * NN + n)) * 1024 + h * 64 + d;
        float4 fv = *reinterpret_cast<const float4*>(vpre + goff);
        tile[nr][d + 0] = f2bf(fv.x);
        tile[nr][d + 1] = f2bf(fv.y);
        tile[nr][d + 2] = f2bf(fv.z);
        tile[nr][d + 3] = f2bf(fv.w);
        float4 fp = *reinterpret_cast<const float4*>(ppre + goff);
        us4 up; up[0] = f2bf(fp.x); up[1] = f2bf(fp.y); up[2] = f2bf(fp.z); up[3] = f2bf(fp.w);
        *reinterpret_cast<us4*>(KK + ((size_t)(b * NH + h) * NN + n) * 128 + swzc(n, 64 + d)) = up;
    }
    __syncthreads();
    size_t vbase = (size_t)(b * NH + h) * 64 * NN;
    int n = n0 + lane;
#pragma unroll
    for (int j = 0; j < 16; j++) {
        int d = w + j * 4;
        int nsw = (n & ~127) | (((((n & 127) >> 3) ^ (d & 7)) << 3)) | (n & 7);
        Vt[vbase + (size_t)d * NN + nsw] = tile[lane][d];
    }
}

// ---------------- flash attention: S = QQ·KK^T (K=128), exp2 softmax, O = P·V ----------------
__global__ __launch_bounds__(256) void flash_attn(const u16* __restrict__ QQ,
                                                  const u16* __restrict__ KK,
                                                  const u16* __restrict__ Vt,
                                                  u16* __restrict__ ctx) {
    __shared__ u16 KKs[2][128 * 128];  // 2 x 32KB
    __shared__ u16 Vts[2][64 * 128];   // 2 x 16KB
    __shared__ u16 Ps[4][32 * 64];     // 16KB per-wave P half-strips
    int qt = blockIdx.x, h = blockIdx.y, b = blockIdx.z;
    int n0 = qt * 128;
    int t = threadIdx.x, lane = t & 63, w = t >> 6;
    int lr = lane & 15, lg = lane >> 4;
    const u16* QQg = QQ + ((size_t)(b * NH + h) * NN) * 128;
    const u16* KKg = KK + ((size_t)(b * NH + h) * NN) * 128;
    const u16* Vtg = Vt + ((size_t)(b * NH + h) * 64) * NN;

    // prologue: stage Q -> KKs[0], K(t0) -> KKs[1], V(t0) -> Vts[1]
    {
        const char* srcQ = (const char*)(QQg + (size_t)n0 * 128) + w * 8192 + lane * 16;
        char* dstQ = (char*)KKs[0] + w * 8192;
#pragma unroll
        for (int i = 0; i < 8; i++) gload16(srcQ + i * 1024, dstQ + i * 1024);
        const char* srcK = (const char*)KKg + w * 8192 + lane * 16;
        char* dstK = (char*)KKs[1] + w * 8192;
#pragma unroll
        for (int i = 0; i < 8; i++) gload16(srcK + i * 1024, dstK + i * 1024);
#pragma unroll
        for (int i = 0; i < 4; i++) {
            int oo = w * 4096 + i * 1024 + lane * 16;
            int row = oo >> 8, rem = oo & 255;
            gload16((const char*)Vtg + (size_t)row * 4096 + rem,
                    (char*)Vts[1] + w * 4096 + i * 1024);
        }
    }
    __syncthreads();
    short8 aq[2][4];
#pragma unroll
    for (int rt = 0; rt < 2; rt++)
#pragma unroll
        for (int ks = 0; ks < 4; ks++) {
            int row = w * 32 + rt * 16 + lr;
            aq[rt][ks] = *reinterpret_cast<const short8*>(
                KKs[0] + row * 128 + (((ks * 4 + lg) ^ (row & 7)) << 3));
        }
    __syncthreads();   // all waves done reading Q region before tile-1 stage overwrites it

    f32x4 O[2][4] = {};
    float mrun[2][4], lrun[2][4];
#pragma unroll
    for (int rt = 0; rt < 2; rt++)
#pragma unroll
        for (int rg = 0; rg < 4; rg++) { mrun[rt][rg] = -1e30f; lrun[rt][rg] = 0.f; }

    int cur = 1;
    for (int tt = 0; tt < 16; tt++) {
        // issue next-tile stage BEFORE compute (latency hidden under MFMA+softmax)
        if (tt < 15) {
            int m1 = (tt + 1) << 7;
            const char* srcK = (const char*)KKg + (size_t)m1 * 256 + w * 8192 + lane * 16;
            char* dstK = (char*)KKs[cur ^ 1] + w * 8192;
#pragma unroll
            for (int i = 0; i < 8; i++) gload16(srcK + i * 1024, dstK + i * 1024);
#pragma unroll
            for (int i = 0; i < 4; i++) {
                int oo = w * 4096 + i * 1024 + lane * 16;
                int row = oo >> 8, rem = oo & 255;
                gload16((const char*)Vtg + (size_t)row * 4096 + (size_t)m1 * 2 + rem,
                        (char*)Vts[cur ^ 1] + w * 4096 + i * 1024);
            }
        }
        const u16* Kc = KKs[cur];
        const u16* Vc = Vts[cur];
        // S = QQ·KK^T  (32 rows per wave x 128 cols), scale+log2e pre-folded into Q
        f32x4 S[2][8];
#pragma unroll
        for (int ct = 0; ct < 8; ct++) {
            short8 bk[4];
#pragma unroll
            for (int ks = 0; ks < 4; ks++) {
                int row = ct * 16 + lr;
                bk[ks] = *reinterpret_cast<const short8*>(
                    Kc + row * 128 + (((ks * 4 + lg) ^ (row & 7)) << 3));
            }
#pragma unroll
            for (int rt = 0; rt < 2; rt++) {
                f32x4 s = {};
#pragma unroll
                for (int ks = 0; ks < 4; ks++)
                    s = __builtin_amdgcn_mfma_f32_16x16x32_bf16(aq[rt][ks], bk[ks], s, 0, 0, 0);
                S[rt][ct] = s;
            }
        }
        // online softmax (exp2 domain); rows owned by (lg, rg, rt); reduce over lr lanes
#pragma unroll
        for (int rt = 0; rt < 2; rt++) {
#pragma unroll
            for (int rg = 0; rg < 4; rg++) {
                float mx = -1e30f;
#pragma unroll
                for (int ct = 0; ct < 8; ct++) mx = fmaxf(mx, S[rt][ct][rg]);
#pragma unroll
                for (int mk = 1; mk < 16; mk <<= 1) mx = fmaxf(mx, __shfl_xor(mx, mk));
                float newm = fmaxf(mrun[rt][rg], mx);
                float sf = exp2f(mrun[rt][rg] - newm);
                float ls = 0.f;
#pragma unroll
                for (int ct = 0; ct < 8; ct++) {
                    float p = exp2f(S[rt][ct][rg] - newm);
                    S[rt][ct][rg] = p;
                    ls += p;
                }
#pragma unroll
                for (int mk = 1; mk < 16; mk <<= 1) ls += __shfl_xor(ls, mk);
                lrun[rt][rg] = lrun[rt][rg] * sf + ls;
                mrun[rt][rg] = newm;
#pragma unroll
                for (int dt = 0; dt < 4; dt++) O[rt][dt][rg] *= sf;
            }
        }
        // P -> per-wave LDS half-strip [32][64], two k-halves
        u16* Pw = Ps[w];
#pragma unroll
        for (int half = 0; half < 2; half++) {
#pragma unroll
            for (int rt = 0; rt < 2; rt++)
#pragma unroll
                for (int ctl = 0; ctl < 4; ctl++) {
                    int c = ctl * 16 + lr;
#pragma unroll
                    for (int rg = 0; rg < 4; rg++) {
                        int row = rt * 16 + lg * 4 + rg;
                        Pw[row * 64 + ((((c >> 3) ^ (row & 7)) << 3) | (c & 7))] =
                            f2bf(S[rt][half * 4 + ctl][rg]);
                    }
                }
            short8 pa[2][2];
#pragma unroll
            for (int rt = 0; rt < 2; rt++)
#pragma unroll
                for (int ksl = 0; ksl < 2; ksl++) {
                    int row = rt * 16 + lr;
                    pa[rt][ksl] = *reinterpret_cast<const short8*>(
                        Pw + row * 64 + (((ksl * 4 + lg) ^ (row & 7)) << 3));
                }
#pragma unroll
            for (int dt = 0; dt < 4; dt++) {
#pragma unroll
                for (int ksl = 0; ksl < 2; ksl++) {
                    int ks = half * 2 + ksl;
                    int vrow = dt * 16 + lr;
                    short8 vf = *reinterpret_cast<const short8*>(
                        Vc + vrow * 128 + (((ks * 4 + lg) ^ (vrow & 7)) << 3));
#pragma unroll
                    for (int rt = 0; rt < 2; rt++)
                        O[rt][dt] = __builtin_amdgcn_mfma_f32_16x16x32_bf16(pa[rt][ksl], vf, O[rt][dt], 0, 0, 0);
                }
            }
        }
        __syncthreads();   // drains next-tile stage (covered by compute) + all LDS reads
        cur ^= 1;
    }
    // epilogue: normalize, write ctx [B*N][C] bf16 (linear layout)
#pragma unroll
    for (int rt = 0; rt < 2; rt++) {
#pragma unroll
        for (int dt = 0; dt < 4; dt++) {
#pragma unroll
            for (int rg = 0; rg < 4; rg++) {
                int n = n0 + w * 32 + rt * 16 + lg * 4 + rg;
                float oo = O[rt][dt][rg] / lrun[rt][rg];
                ctx[((size_t)(b * NN) + n) * 1024 + h * 64 + dt * 16 + lr] = f2bf(oo);
            }
        }
    }
}

extern "C" void kernel_launch(void* const* d_in, const int* in_sizes, int n_in,
                              void* d_out, int out_size, void* d_ws, size_t ws_size,
                              hipStream_t stream) {
    const float* x   = (const float*)d_in[0];
    const float* pos = (const float*)d_in[2];
    const float* Wq  = (const float*)d_in[3];
    const float* bq  = (const float*)d_in[4];
    const float* Wk  = (const float*)d_in[5];
    const float* bk  = (const float*)d_in[6];
    const float* Wv  = (const float*)d_in[7];
    const float* bv  = (const float*)d_in[8];
    const float* Wo  = (const float*)d_in[9];
    const float* bo  = (const float*)d_in[10];
    const float* qlw = (const float*)d_in[11];
    const float* qlb = (const float*)d_in[12];
    const float* klw = (const float*)d_in[13];
    const float* klb = (const float*)d_in[14];
    const float* Wp  = (const float*)d_in[15];
    const float* pbu = (const float*)d_in[16];
    const float* pbv = (const float*)d_in[17];
    float* out = (float*)d_out;

    char* ws = (char*)d_ws;
    u16*   xbf   = (u16*)(ws);                      //  8388608 B
    u16*   posbf = (u16*)(ws + 8388608);            //  8388608 B
    u16*   Wbf   = (u16*)(ws + 16777216);           //  5 x 2097152 B (q,k,v,p,o)
    float* pre   = (float*)(ws + 27262976);         //  4 x 16777216 B (q,k,v,p)
    u16*   QQ    = (u16*)(ws + 94371840);           // 16777216 B
    u16*   KK    = (u16*)(ws + 111149056);          // 16777216 B
    u16*   Vt    = (u16*)(ws + 127926272);          //  8388608 B
    u16*   ctx   = (u16*)(ws + 136314880);          //  8388608 B  (total 144703488)

    cast_kernel<<<4096, 256, 0, stream>>>(x, xbf, 1048576);
    cast_kernel<<<4096, 256, 0, stream>>>(pos, posbf, 1048576);
    cast_kernel<<<1024, 256, 0, stream>>>(Wq, Wbf + 0 * 1048576, 262144);
    cast_kernel<<<1024, 256, 0, stream>>>(Wk, Wbf + 1 * 1048576, 262144);
    cast_kernel<<<1024, 256, 0, stream>>>(Wv, Wbf + 2 * 1048576, 262144);
    cast_kernel<<<1024, 256, 0, stream>>>(Wp, Wbf + 3 * 1048576, 262144);
    cast_kernel<<<1024, 256, 0, stream>>>(Wo, Wbf + 4 * 1048576, 262144);

    proj_gemm<<<dim3(8, 32, 4), 256, 0, stream>>>(xbf, posbf, Wbf, pre, bq, bk, bv);
    post_qk<<<dim3(1024, 2), 256, 0, stream>>>(pre, qlw, qlb, klw, klb, pbu, pbv, QQ, KK);
    post_vp<<<dim3(32, 32), 256, 0, stream>>>(pre + (size_t)2 * 4194304, pre + (size_t)3 * 4194304, Vt, KK);
    flash_attn<<<dim3(16, 16, 2), 256, 0, stream>>>(QQ, KK, Vt, ctx);
    out_gemm<<<dim3(8, 32), 256, 0, stream>>>(ctx, Wbf + 4 * 1048576, out, bo);
}

// Round 7
// 261.186 us; speedup vs baseline: 1.2753x; 1.2753x over previous
//
#include <hip/hip_runtime.h>
#include <stdint.h>

// WhaleAttention: B=2 N=2048 C=1024 H=16 D=64
// R7: flash rebuilt for TLP: 512-thr blocks (8 waves x 16 q-rows), KVBLK=64,
// K+V dbuf issue-early, 64KB LDS -> 2 blocks/CU = 4 waves/SIMD, setprio on MFMA.

typedef short short8 __attribute__((ext_vector_type(8)));
typedef float f32x4 __attribute__((ext_vector_type(4)));
typedef unsigned short us4 __attribute__((ext_vector_type(4)));
typedef unsigned short u16;

#define NB 2
#define NN 2048
#define NC 1024
#define NH 16
#define ND 64

__device__ __forceinline__ u16 f2bf(float f) {
    unsigned int u = __float_as_uint(f);
    u += 0x7fffu + ((u >> 16) & 1u);
    return (u16)(u >> 16);
}

// swizzled column for a 128-u16 row: permute 16B chunks by XOR(row&7). involution.
__device__ __forceinline__ int swzc(int row, int c) {
    return (((c >> 3) ^ (row & 7)) << 3) | (c & 7);
}

__device__ __forceinline__ void gload16(const void* g, void* l) {
    __builtin_amdgcn_global_load_lds(
        (const __attribute__((address_space(1))) unsigned int*)g,
        (__attribute__((address_space(3))) unsigned int*)l, 16, 0, 0);
}

// ---------------- cast fp32 -> bf16 ----------------
__global__ __launch_bounds__(256) void cast_kernel(const float* __restrict__ src,
                                                   u16* __restrict__ dst, int n4) {
    int i = blockIdx.x * 256 + threadIdx.x;
    if (i < n4) {
        float4 f = reinterpret_cast<const float4*>(src)[i];
        us4 o;
        o[0] = f2bf(f.x); o[1] = f2bf(f.y); o[2] = f2bf(f.z); o[3] = f2bf(f.w);
        reinterpret_cast<us4*>(dst)[i] = o;
    }
}

// ---------------- GEMM C = A @ W^T (+bias), out fp32; gload_lds + dbuf ----------------
__device__ __forceinline__ void gemm_stage(const u16* __restrict__ A,
                                           const u16* __restrict__ W,
                                           u16* As, u16* Bs,
                                           int m0, int n0, int kk, int w, int lane) {
    int lr4 = lane >> 2, lc8 = (lane & 3) * 8;
#pragma unroll
    for (int i = 0; i < 2; i++) {
        int rbase = w * 32 + i * 16;
        gload16(A + (size_t)(m0 + rbase + lr4) * 1024 + kk + lc8, As + rbase * 32);
        gload16(W + (size_t)(n0 + rbase + lr4) * 1024 + kk + lc8, Bs + rbase * 32);
    }
}

__device__ __forceinline__ void gemm_bt_body(const u16* __restrict__ A,
                                             const u16* __restrict__ W,
                                             float* __restrict__ out,
                                             const float* __restrict__ bias,
                                             int m0, int n0) {
    __shared__ u16 As[2][128 * 32];
    __shared__ u16 Bs[2][128 * 32];
    int t = threadIdx.x, lane = t & 63, w = t >> 6;
    int wm = (w >> 1) * 64, wn = (w & 1) * 64;
    int lr = lane & 15, lg = lane >> 4;
    f32x4 acc[4][4] = {};

    gemm_stage(A, W, As[0], Bs[0], m0, n0, 0, w, lane);
    __syncthreads();
    int cur = 0;
    for (int kt = 0; kt < 32; kt++) {
        if (kt < 31)
            gemm_stage(A, W, As[cur ^ 1], Bs[cur ^ 1], m0, n0, (kt + 1) * 32, w, lane);
        const u16* Ac = As[cur];
        const u16* Bc = Bs[cur];
        short8 af[4], bw[4];
#pragma unroll
        for (int mt = 0; mt < 4; mt++)
            af[mt] = *reinterpret_cast<const short8*>(Ac + (wm + mt * 16 + lr) * 32 + lg * 8);
#pragma unroll
        for (int nt = 0; nt < 4; nt++)
            bw[nt] = *reinterpret_cast<const short8*>(Bs[cur] + (wn + nt * 16 + lr) * 32 + lg * 8);
#pragma unroll
        for (int mt = 0; mt < 4; mt++)
#pragma unroll
            for (int nt = 0; nt < 4; nt++)
                acc[mt][nt] = __builtin_amdgcn_mfma_f32_16x16x32_bf16(af[mt], bw[nt], acc[mt][nt], 0, 0, 0);
        __syncthreads();
        cur ^= 1;
    }
#pragma unroll
    for (int mt = 0; mt < 4; mt++) {
#pragma unroll
        for (int nt = 0; nt < 4; nt++) {
            int c = n0 + wn + nt * 16 + lr;
            float badd = bias ? bias[c] : 0.0f;
            int r = m0 + wm + mt * 16 + lg * 4;
#pragma unroll
            for (int rg = 0; rg < 4; rg++)
                out[(size_t)(r + rg) * 1024 + c] = acc[mt][nt][rg] + badd;
        }
    }
}

// z=0:q(bq) 1:k(bk) 2:v(bv) 3:p(none, A=pos)
__global__ __launch_bounds__(256) void proj_gemm(const u16* __restrict__ xbf,
                                                 const u16* __restrict__ posbf,
                                                 const u16* __restrict__ Wbase,
                                                 float* __restrict__ prebase,
                                                 const float* __restrict__ bq,
                                                 const float* __restrict__ bk,
                                                 const float* __restrict__ bv) {
    int z = blockIdx.z;
    const u16* A = (z == 3) ? posbf : xbf;
    const u16* W = Wbase + (size_t)z * 1048576;
    float* out = prebase + (size_t)z * 4194304;
    const float* bias = (z == 0) ? bq : ((z == 1) ? bk : ((z == 2) ? bv : (const float*)nullptr));
    gemm_bt_body(A, W, out, bias, blockIdx.y * 128, blockIdx.x * 128);
}

__global__ __launch_bounds__(256) void out_gemm(const u16* __restrict__ ctx,
                                                const u16* __restrict__ Wo,
                                                float* __restrict__ out,
                                                const float* __restrict__ bo) {
    gemm_bt_body(ctx, Wo, out, bo, blockIdx.y * 128, blockIdx.x * 128);
}

// ---------------- LN on q/k rows; QQ=[s*(q^+u) | s*(q^+v)], KK[:,0:64]=k^  (pre-swizzled)
//   s = 0.125 * log2(e)  (softmax runs in exp2 domain) ----------------
__global__ __launch_bounds__(256) void post_qk(const float* __restrict__ prebase,
                                               const float* __restrict__ qw, const float* __restrict__ qb,
                                               const float* __restrict__ kw, const float* __restrict__ kb,
                                               const float* __restrict__ pbu, const float* __restrict__ pbv,
                                               u16* __restrict__ QQ, u16* __restrict__ KK) {
    const float QSC = 0.125f * 1.44269504089f;
    int isq = (blockIdx.y == 0);
    const float* pre = prebase + (isq ? 0 : (size_t)4194304);
    const float* lw = isq ? qw : kw;
    const float* lb = isq ? qb : kb;
    int wv = threadIdx.x >> 6, lane = threadIdx.x & 63;
    int row = blockIdx.x * 4 + wv;   // 0..4095
    int b = row >> 11, n = row & 2047;
    const float* pr = pre + (size_t)row * 1024;
    float vals[16];
    float s = 0.f, s2 = 0.f;
#pragma unroll
    for (int i = 0; i < 4; i++) {
        float4 f = *reinterpret_cast<const float4*>(pr + i * 256 + lane * 4);
        vals[i * 4 + 0] = f.x; vals[i * 4 + 1] = f.y; vals[i * 4 + 2] = f.z; vals[i * 4 + 3] = f.w;
        s += f.x + f.y + f.z + f.w;
        s2 += f.x * f.x + f.y * f.y + f.z * f.z + f.w * f.w;
    }
#pragma unroll
    for (int m = 1; m < 64; m <<= 1) { s += __shfl_xor(s, m); s2 += __shfl_xor(s2, m); }
    float mean = s * (1.f / 1024.f);
    float var = s2 * (1.f / 1024.f) - mean * mean;
    float inv = rsqrtf(var + 1e-6f);
#pragma unroll
    for (int i = 0; i < 4; i++) {
        int c0 = i * 256 + lane * 4;
        int h = c0 >> 6, d0 = c0 & 63;
        size_t base = ((size_t)(b * NH + h) * NN + n) * 128;
        if (isq) {
            us4 u0, u1;
#pragma unroll
            for (int j = 0; j < 4; j++) {
                float xn = (vals[i * 4 + j] - mean) * inv * lw[c0 + j] + lb[c0 + j];
                u0[j] = f2bf((xn + pbu[h * 64 + d0 + j]) * QSC);
                u1[j] = f2bf((xn + pbv[h * 64 + d0 + j]) * QSC);
            }
            *reinterpret_cast<us4*>(QQ + base + swzc(n, d0)) = u0;
            *reinterpret_cast<us4*>(QQ + base + swzc(n, d0 + 64)) = u1;
        } else {
            us4 u0;
#pragma unroll
            for (int j = 0; j < 4; j++) {
                float xn = (vals[i * 4 + j] - mean) * inv * lw[c0 + j] + lb[c0 + j];
                u0[j] = f2bf(xn);
            }
            *reinterpret_cast<us4*>(KK + base + swzc(n, d0)) = u0;
        }
    }
}

// ---------------- v -> Vt[b][h][d][n] (pre-swizzled: 8-elem chunks in 64-col windows,
//                  key d&7), p -> KK[:,64:128] (pre-swizzled by n) ----------------
__global__ __launch_bounds__(256) void post_vp(const float* __restrict__ vpre,
                                               const float* __restrict__ ppre,
                                               u16* __restrict__ Vt, u16* __restrict__ KK) {
    __shared__ u16 tile[64][66];
    int bh = blockIdx.x;               // 0..31
    int b = bh >> 4, h = bh & 15;
    int n0 = blockIdx.y * 64;
    int t = threadIdx.x, lane = t & 63, w = t >> 6;
#pragma unroll
    for (int j = 0; j < 4; j++) {
        int nr = t >> 2;                 // 0..63
        int d = (t & 3) * 16 + j * 4;    // 0..63
        int n = n0 + nr;
        size_t goff = ((size_t)(b * NN + n)) * 1024 + h * 64 + d;
        float4 fv = *reinterpret_cast<const float4*>(vpre + goff);
        tile[nr][d + 0] = f2bf(fv.x);
        tile[nr][d + 1] = f2bf(fv.y);
        tile[nr][d + 2] = f2bf(fv.z);
        tile[nr][d + 3] = f2bf(fv.w);
        float4 fp = *reinterpret_cast<const float4*>(ppre + goff);
        us4 up; up[0] = f2bf(fp.x); up[1] = f2bf(fp.y); up[2] = f2bf(fp.z); up[3] = f2bf(fp.w);
        *reinterpret_cast<us4*>(KK + ((size_t)(b * NH + h) * NN + n) * 128 + swzc(n, 64 + d)) = up;
    }
    __syncthreads();
    size_t vbase = (size_t)(b * NH + h) * 64 * NN;
    int n = n0 + lane;
#pragma unroll
    for (int j = 0; j < 16; j++) {
        int d = w + j * 4;
        // 64-col window, 8-elem (16B) chunks, XOR key d&7
        int nsw = (n & ~63) | ((((n >> 3) & 7) ^ (d & 7)) << 3) | (n & 7);
        Vt[vbase + (size_t)d * NN + nsw] = tile[lane][d];
    }
}

// ---------------- flash attention: 8 waves x 16 q-rows, KVBLK=64, K/V dbuf ----------------
__global__ __launch_bounds__(512, 4) void flash_attn(const u16* __restrict__ QQ,
                                                     const u16* __restrict__ KK,
                                                     const u16* __restrict__ Vt,
                                                     u16* __restrict__ ctx) {
    __shared__ u16 KQs[2 * 64 * 128];   // K dbuf (2x16KB); prologue holds Q 128x128 flat
    __shared__ u16 Vts[2 * 64 * 64];    // V dbuf (2x8KB)
    __shared__ u16 Ps[8 * 16 * 64];     // per-wave P strips (8x2KB)
    int qt = blockIdx.x, h = blockIdx.y, b = blockIdx.z;
    int n0 = qt * 128;
    int t = threadIdx.x, lane = t & 63, w = t >> 6;   // w: 0..7
    int lr = lane & 15, lg = lane >> 4;
    const char* QQg = (const char*)(QQ + ((size_t)(b * NH + h) * NN) * 128);
    const char* KKg = (const char*)(KK + ((size_t)(b * NH + h) * NN) * 128);
    const char* Vtg = (const char*)(Vt + ((size_t)(b * NH + h) * 64) * NN);

    // prologue: stage full Q tile (32KB) flat into KQs
#pragma unroll
    for (int i = 0; i < 4; i++)
        gload16(QQg + (size_t)n0 * 256 + i * 8192 + w * 1024 + lane * 16,
                (char*)KQs + i * 8192 + w * 1024);
    __syncthreads();
    short8 aq[4];
    {
        int row = w * 16 + lr;   // 0..127
#pragma unroll
        for (int ks = 0; ks < 4; ks++)
            aq[ks] = *reinterpret_cast<const short8*>(
                KQs + row * 128 + (((ks * 4 + lg) ^ (row & 7)) << 3));
    }
    __syncthreads();   // everyone holds Q frags; buffers free

    // stage tile 0 into buf 0
#pragma unroll
    for (int i = 0; i < 2; i++)
        gload16(KKg + i * 8192 + w * 1024 + lane * 16, (char*)KQs + i * 8192 + w * 1024);
    gload16(Vtg + (size_t)(w * 8 + (lane >> 3)) * (NN * 2) + (lane & 7) * 16,
            (char*)Vts + w * 1024);
    __syncthreads();

    f32x4 O[4] = {};
    float mrun[4], lrun[4];
#pragma unroll
    for (int rg = 0; rg < 4; rg++) { mrun[rg] = -1e30f; lrun[rg] = 0.f; }

    int cur = 0;
    for (int tt = 0; tt < 32; tt++) {
        // issue next-tile stage early (latency hidden under this tile's compute)
        if (tt < 31) {
            int m1 = (tt + 1) * 64;
            int nb = cur ^ 1;
#pragma unroll
            for (int i = 0; i < 2; i++)
                gload16(KKg + (size_t)m1 * 256 + i * 8192 + w * 1024 + lane * 16,
                        (char*)KQs + nb * 16384 + i * 8192 + w * 1024);
            gload16(Vtg + (size_t)(w * 8 + (lane >> 3)) * (NN * 2) + (size_t)m1 * 2 + (lane & 7) * 16,
                    (char*)Vts + nb * 8192 + w * 1024);
        }
        const u16* Kc = KQs + cur * 8192;
        const u16* Vc = Vts + cur * 4096;
        // S = QQ·KK^T  (16 q-rows/wave x 64 kv cols), scale+log2e pre-folded into Q
        f32x4 S[4];
        __builtin_amdgcn_s_setprio(1);
#pragma unroll
        for (int ct = 0; ct < 4; ct++) {
            f32x4 s = {};
#pragma unroll
            for (int ks = 0; ks < 4; ks++) {
                int row = ct * 16 + lr;
                short8 bk = *reinterpret_cast<const short8*>(
                    Kc + row * 128 + (((ks * 4 + lg) ^ (row & 7)) << 3));
                s = __builtin_amdgcn_mfma_f32_16x16x32_bf16(aq[ks], bk, s, 0, 0, 0);
            }
            S[ct] = s;
        }
        __builtin_amdgcn_s_setprio(0);
        // online softmax (exp2 domain); q-row = lg*4+rg, reduce over lr lanes (kv)
#pragma unroll
        for (int rg = 0; rg < 4; rg++) {
            float mx = fmaxf(fmaxf(S[0][rg], S[1][rg]), fmaxf(S[2][rg], S[3][rg]));
#pragma unroll
            for (int mk = 1; mk < 16; mk <<= 1) mx = fmaxf(mx, __shfl_xor(mx, mk));
            float newm = fmaxf(mrun[rg], mx);
            float sf = exp2f(mrun[rg] - newm);
            float ls = 0.f;
#pragma unroll
            for (int ct = 0; ct < 4; ct++) {
                float p = exp2f(S[ct][rg] - newm);
                S[ct][rg] = p;
                ls += p;
            }
#pragma unroll
            for (int mk = 1; mk < 16; mk <<= 1) ls += __shfl_xor(ls, mk);
            lrun[rg] = lrun[rg] * sf + ls;
            mrun[rg] = newm;
#pragma unroll
            for (int dt = 0; dt < 4; dt++) O[dt][rg] *= sf;
        }
        // P -> per-wave LDS strip [16][64] (swizzled), then PV
        u16* Pw = Ps + w * 1024;
#pragma unroll
        for (int ct = 0; ct < 4; ct++) {
            int c = ct * 16 + lr;
#pragma unroll
            for (int rg = 0; rg < 4; rg++) {
                int row = lg * 4 + rg;
                Pw[row * 64 + ((((c >> 3) ^ (row & 7)) << 3) | (c & 7))] = f2bf(S[ct][rg]);
            }
        }
        short8 pa[2];
#pragma unroll
        for (int ks = 0; ks < 2; ks++)
            pa[ks] = *reinterpret_cast<const short8*>(
                Pw + lr * 64 + (((ks * 4 + lg) ^ (lr & 7)) << 3));
        __builtin_amdgcn_s_setprio(1);
#pragma unroll
        for (int dt = 0; dt < 4; dt++) {
#pragma unroll
            for (int ks = 0; ks < 2; ks++) {
                int vrow = dt * 16 + lr;
                short8 vf = *reinterpret_cast<const short8*>(
                    Vc + vrow * 64 + (((ks * 4 + lg) ^ (vrow & 7)) << 3));
                O[dt] = __builtin_amdgcn_mfma_f32_16x16x32_bf16(pa[ks], vf, O[dt], 0, 0, 0);
            }
        }
        __builtin_amdgcn_s_setprio(0);
        __syncthreads();   // drains next-tile stage (covered) + LDS reads of cur
        cur ^= 1;
    }
    // epilogue: normalize, write ctx [B*N][C] bf16 (linear layout)
#pragma unroll
    for (int dt = 0; dt < 4; dt++) {
#pragma unroll
        for (int rg = 0; rg < 4; rg++) {
            int n = n0 + w * 16 + lg * 4 + rg;
            float oo = O[dt][rg] / lrun[rg];
            ctx[((size_t)(b * NN) + n) * 1024 + h * 64 + dt * 16 + lr] = f2bf(oo);
        }
    }
}

extern "C" void kernel_launch(void* const* d_in, const int* in_sizes, int n_in,
                              void* d_out, int out_size, void* d_ws, size_t ws_size,
                              hipStream_t stream) {
    const float* x   = (const float*)d_in[0];
    const float* pos = (const float*)d_in[2];
    const float* Wq  = (const float*)d_in[3];
    const float* bq  = (const float*)d_in[4];
    const float* Wk  = (const float*)d_in[5];
    const float* bk  = (const float*)d_in[6];
    const float* Wv  = (const float*)d_in[7];
    const float* bv  = (const float*)d_in[8];
    const float* Wo  = (const float*)d_in[9];
    const float* bo  = (const float*)d_in[10];
    const float* qlw = (const float*)d_in[11];
    const float* qlb = (const float*)d_in[12];
    const float* klw = (const float*)d_in[13];
    const float* klb = (const float*)d_in[14];
    const float* Wp  = (const float*)d_in[15];
    const float* pbu = (const float*)d_in[16];
    const float* pbv = (const float*)d_in[17];
    float* out = (float*)d_out;

    char* ws = (char*)d_ws;
    u16*   xbf   = (u16*)(ws);                      //  8388608 B
    u16*   posbf = (u16*)(ws + 8388608);            //  8388608 B
    u16*   Wbf   = (u16*)(ws + 16777216);           //  5 x 2097152 B (q,k,v,p,o)
    float* pre   = (float*)(ws + 27262976);         //  4 x 16777216 B (q,k,v,p)
    u16*   QQ    = (u16*)(ws + 94371840);           // 16777216 B
    u16*   KK    = (u16*)(ws + 111149056);          // 16777216 B
    u16*   Vt    = (u16*)(ws + 127926272);          //  8388608 B
    u16*   ctx   = (u16*)(ws + 136314880);          //  8388608 B  (total 144703488)

    cast_kernel<<<4096, 256, 0, stream>>>(x, xbf, 1048576);
    cast_kernel<<<4096, 256, 0, stream>>>(pos, posbf, 1048576);
    cast_kernel<<<1024, 256, 0, stream>>>(Wq, Wbf + 0 * 1048576, 262144);
    cast_kernel<<<1024, 256, 0, stream>>>(Wk, Wbf + 1 * 1048576, 262144);
    cast_kernel<<<1024, 256, 0, stream>>>(Wv, Wbf + 2 * 1048576, 262144);
    cast_kernel<<<1024, 256, 0, stream>>>(Wp, Wbf + 3 * 1048576, 262144);
    cast_kernel<<<1024, 256, 0, stream>>>(Wo, Wbf + 4 * 1048576, 262144);

    proj_gemm<<<dim3(8, 32, 4), 256, 0, stream>>>(xbf, posbf, Wbf, pre, bq, bk, bv);
    post_qk<<<dim3(1024, 2), 256, 0, stream>>>(pre, qlw, qlb, klw, klb, pbu, pbv, QQ, KK);
    post_vp<<<dim3(32, 32), 256, 0, stream>>>(pre + (size_t)2 * 4194304, pre + (size_t)3 * 4194304, Vt, KK);
    flash_attn<<<dim3(16, 16, 2), 512, 0, stream>>>(QQ, KK, Vt, ctx);
    out_gemm<<<dim3(8, 32), 256, 0, stream>>>(ctx, Wbf + 4 * 1048576, out, bo);
}

// Round 8
// 243.663 us; speedup vs baseline: 1.3670x; 1.0719x over previous
//
#include <hip/hip_runtime.h>
#include <stdint.h>

// WhaleAttention: B=2 N=2048 C=1024 H=16 D=64
// R8: flash softmax VALU cuts: (1) row-sum via ones-MFMA (O5 accumulator, deletes
// 16 shuffle-sum + adds/tile), (2) T13 defer-max THR=8 exp2-domain (skips rescale
// on most tiles). Structure/geometry unchanged from R7 (8 waves x 16 q, KVBLK=64).

typedef short short8 __attribute__((ext_vector_type(8)));
typedef float f32x4 __attribute__((ext_vector_type(4)));
typedef unsigned short us4 __attribute__((ext_vector_type(4)));
typedef unsigned short u16;

#define NB 2
#define NN 2048
#define NC 1024
#define NH 16
#define ND 64

__device__ __forceinline__ u16 f2bf(float f) {
    unsigned int u = __float_as_uint(f);
    u += 0x7fffu + ((u >> 16) & 1u);
    return (u16)(u >> 16);
}

// swizzled column for a 128-u16 row: permute 16B chunks by XOR(row&7). involution.
__device__ __forceinline__ int swzc(int row, int c) {
    return (((c >> 3) ^ (row & 7)) << 3) | (c & 7);
}

__device__ __forceinline__ void gload16(const void* g, void* l) {
    __builtin_amdgcn_global_load_lds(
        (const __attribute__((address_space(1))) unsigned int*)g,
        (__attribute__((address_space(3))) unsigned int*)l, 16, 0, 0);
}

// ---------------- cast fp32 -> bf16 ----------------
__global__ __launch_bounds__(256) void cast_kernel(const float* __restrict__ src,
                                                   u16* __restrict__ dst, int n4) {
    int i = blockIdx.x * 256 + threadIdx.x;
    if (i < n4) {
        float4 f = reinterpret_cast<const float4*>(src)[i];
        us4 o;
        o[0] = f2bf(f.x); o[1] = f2bf(f.y); o[2] = f2bf(f.z); o[3] = f2bf(f.w);
        reinterpret_cast<us4*>(dst)[i] = o;
    }
}

// ---------------- GEMM C = A @ W^T (+bias), out fp32; gload_lds + dbuf ----------------
__device__ __forceinline__ void gemm_stage(const u16* __restrict__ A,
                                           const u16* __restrict__ W,
                                           u16* As, u16* Bs,
                                           int m0, int n0, int kk, int w, int lane) {
    int lr4 = lane >> 2, lc8 = (lane & 3) * 8;
#pragma unroll
    for (int i = 0; i < 2; i++) {
        int rbase = w * 32 + i * 16;
        gload16(A + (size_t)(m0 + rbase + lr4) * 1024 + kk + lc8, As + rbase * 32);
        gload16(W + (size_t)(n0 + rbase + lr4) * 1024 + kk + lc8, Bs + rbase * 32);
    }
}

__device__ __forceinline__ void gemm_bt_body(const u16* __restrict__ A,
                                             const u16* __restrict__ W,
                                             float* __restrict__ out,
                                             const float* __restrict__ bias,
                                             int m0, int n0) {
    __shared__ u16 As[2][128 * 32];
    __shared__ u16 Bs[2][128 * 32];
    int t = threadIdx.x, lane = t & 63, w = t >> 6;
    int wm = (w >> 1) * 64, wn = (w & 1) * 64;
    int lr = lane & 15, lg = lane >> 4;
    f32x4 acc[4][4] = {};

    gemm_stage(A, W, As[0], Bs[0], m0, n0, 0, w, lane);
    __syncthreads();
    int cur = 0;
    for (int kt = 0; kt < 32; kt++) {
        if (kt < 31)
            gemm_stage(A, W, As[cur ^ 1], Bs[cur ^ 1], m0, n0, (kt + 1) * 32, w, lane);
        const u16* Ac = As[cur];
        const u16* Bc = Bs[cur];
        short8 af[4], bw[4];
#pragma unroll
        for (int mt = 0; mt < 4; mt++)
            af[mt] = *reinterpret_cast<const short8*>(Ac + (wm + mt * 16 + lr) * 32 + lg * 8);
#pragma unroll
        for (int nt = 0; nt < 4; nt++)
            bw[nt] = *reinterpret_cast<const short8*>(Bc + (wn + nt * 16 + lr) * 32 + lg * 8);
#pragma unroll
        for (int mt = 0; mt < 4; mt++)
#pragma unroll
            for (int nt = 0; nt < 4; nt++)
                acc[mt][nt] = __builtin_amdgcn_mfma_f32_16x16x32_bf16(af[mt], bw[nt], acc[mt][nt], 0, 0, 0);
        __syncthreads();
        cur ^= 1;
    }
#pragma unroll
    for (int mt = 0; mt < 4; mt++) {
#pragma unroll
        for (int nt = 0; nt < 4; nt++) {
            int c = n0 + wn + nt * 16 + lr;
            float badd = bias ? bias[c] : 0.0f;
            int r = m0 + wm + mt * 16 + lg * 4;
#pragma unroll
            for (int rg = 0; rg < 4; rg++)
                out[(size_t)(r + rg) * 1024 + c] = acc[mt][nt][rg] + badd;
        }
    }
}

// z=0:q(bq) 1:k(bk) 2:v(bv) 3:p(none, A=pos)
__global__ __launch_bounds__(256) void proj_gemm(const u16* __restrict__ xbf,
                                                 const u16* __restrict__ posbf,
                                                 const u16* __restrict__ Wbase,
                                                 float* __restrict__ prebase,
                                                 const float* __restrict__ bq,
                                                 const float* __restrict__ bk,
                                                 const float* __restrict__ bv) {
    int z = blockIdx.z;
    const u16* A = (z == 3) ? posbf : xbf;
    const u16* W = Wbase + (size_t)z * 1048576;
    float* out = prebase + (size_t)z * 4194304;
    const float* bias = (z == 0) ? bq : ((z == 1) ? bk : ((z == 2) ? bv : (const float*)nullptr));
    gemm_bt_body(A, W, out, bias, blockIdx.y * 128, blockIdx.x * 128);
}

__global__ __launch_bounds__(256) void out_gemm(const u16* __restrict__ ctx,
                                                const u16* __restrict__ Wo,
                                                float* __restrict__ out,
                                                const float* __restrict__ bo) {
    gemm_bt_body(ctx, Wo, out, bo, blockIdx.y * 128, blockIdx.x * 128);
}

// ---------------- LN on q/k rows; QQ=[s*(q^+u) | s*(q^+v)], KK[:,0:64]=k^  (pre-swizzled)
//   s = 0.125 * log2(e)  (softmax runs in exp2 domain) ----------------
__global__ __launch_bounds__(256) void post_qk(const float* __restrict__ prebase,
                                               const float* __restrict__ qw, const float* __restrict__ qb,
                                               const float* __restrict__ kw, const float* __restrict__ kb,
                                               const float* __restrict__ pbu, const float* __restrict__ pbv,
                                               u16* __restrict__ QQ, u16* __restrict__ KK) {
    const float QSC = 0.125f * 1.44269504089f;
    int isq = (blockIdx.y == 0);
    const float* pre = prebase + (isq ? 0 : (size_t)4194304);
    const float* lw = isq ? qw : kw;
    const float* lb = isq ? qb : kb;
    int wv = threadIdx.x >> 6, lane = threadIdx.x & 63;
    int row = blockIdx.x * 4 + wv;   // 0..4095
    int b = row >> 11, n = row & 2047;
    const float* pr = pre + (size_t)row * 1024;
    float vals[16];
    float s = 0.f, s2 = 0.f;
#pragma unroll
    for (int i = 0; i < 4; i++) {
        float4 f = *reinterpret_cast<const float4*>(pr + i * 256 + lane * 4);
        vals[i * 4 + 0] = f.x; vals[i * 4 + 1] = f.y; vals[i * 4 + 2] = f.z; vals[i * 4 + 3] = f.w;
        s += f.x + f.y + f.z + f.w;
        s2 += f.x * f.x + f.y * f.y + f.z * f.z + f.w * f.w;
    }
#pragma unroll
    for (int m = 1; m < 64; m <<= 1) { s += __shfl_xor(s, m); s2 += __shfl_xor(s2, m); }
    float mean = s * (1.f / 1024.f);
    float var = s2 * (1.f / 1024.f) - mean * mean;
    float inv = rsqrtf(var + 1e-6f);
#pragma unroll
    for (int i = 0; i < 4; i++) {
        int c0 = i * 256 + lane * 4;
        int h = c0 >> 6, d0 = c0 & 63;
        size_t base = ((size_t)(b * NH + h) * NN + n) * 128;
        if (isq) {
            us4 u0, u1;
#pragma unroll
            for (int j = 0; j < 4; j++) {
                float xn = (vals[i * 4 + j] - mean) * inv * lw[c0 + j] + lb[c0 + j];
                u0[j] = f2bf((xn + pbu[h * 64 + d0 + j]) * QSC);
                u1[j] = f2bf((xn + pbv[h * 64 + d0 + j]) * QSC);
            }
            *reinterpret_cast<us4*>(QQ + base + swzc(n, d0)) = u0;
            *reinterpret_cast<us4*>(QQ + base + swzc(n, d0 + 64)) = u1;
        } else {
            us4 u0;
#pragma unroll
            for (int j = 0; j < 4; j++) {
                float xn = (vals[i * 4 + j] - mean) * inv * lw[c0 + j] + lb[c0 + j];
                u0[j] = f2bf(xn);
            }
            *reinterpret_cast<us4*>(KK + base + swzc(n, d0)) = u0;
        }
    }
}

// ---------------- v -> Vt[b][h][d][n] (pre-swizzled: 8-elem chunks in 64-col windows,
//                  key d&7), p -> KK[:,64:128] (pre-swizzled by n) ----------------
__global__ __launch_bounds__(256) void post_vp(const float* __restrict__ vpre,
                                               const float* __restrict__ ppre,
                                               u16* __restrict__ Vt, u16* __restrict__ KK) {
    __shared__ u16 tile[64][66];
    int bh = blockIdx.x;               // 0..31
    int b = bh >> 4, h = bh & 15;
    int n0 = blockIdx.y * 64;
    int t = threadIdx.x, lane = t & 63, w = t >> 6;
#pragma unroll
    for (int j = 0; j < 4; j++) {
        int nr = t >> 2;                 // 0..63
        int d = (t & 3) * 16 + j * 4;    // 0..63
        int n = n0 + nr;
        size_t goff = ((size_t)(b * NN + n)) * 1024 + h * 64 + d;
        float4 fv = *reinterpret_cast<const float4*>(vpre + goff);
        tile[nr][d + 0] = f2bf(fv.x);
        tile[nr][d + 1] = f2bf(fv.y);
        tile[nr][d + 2] = f2bf(fv.z);
        tile[nr][d + 3] = f2bf(fv.w);
        float4 fp = *reinterpret_cast<const float4*>(ppre + goff);
        us4 up; up[0] = f2bf(fp.x); up[1] = f2bf(fp.y); up[2] = f2bf(fp.z); up[3] = f2bf(fp.w);
        *reinterpret_cast<us4*>(KK + ((size_t)(b * NH + h) * NN + n) * 128 + swzc(n, 64 + d)) = up;
    }
    __syncthreads();
    size_t vbase = (size_t)(b * NH + h) * 64 * NN;
    int n = n0 + lane;
#pragma unroll
    for (int j = 0; j < 16; j++) {
        int d = w + j * 4;
        // 64-col window, 8-elem (16B) chunks, XOR key d&7
        int nsw = (n & ~63) | ((((n >> 3) & 7) ^ (d & 7)) << 3) | (n & 7);
        Vt[vbase + (size_t)d * NN + nsw] = tile[lane][d];
    }
}

// ---------------- flash attention: 8 waves x 16 q-rows, KVBLK=64, K/V dbuf ----------------
__global__ __launch_bounds__(512, 4) void flash_attn(const u16* __restrict__ QQ,
                                                     const u16* __restrict__ KK,
                                                     const u16* __restrict__ Vt,
                                                     u16* __restrict__ ctx) {
    __shared__ u16 KQs[2 * 64 * 128];   // K dbuf (2x16KB); prologue holds Q 128x128 flat
    __shared__ u16 Vts[2 * 64 * 64];    // V dbuf (2x8KB)
    __shared__ u16 Ps[8 * 16 * 64];     // per-wave P strips (8x2KB)
    int qt = blockIdx.x, h = blockIdx.y, b = blockIdx.z;
    int n0 = qt * 128;
    int t = threadIdx.x, lane = t & 63, w = t >> 6;   // w: 0..7
    int lr = lane & 15, lg = lane >> 4;
    const char* QQg = (const char*)(QQ + ((size_t)(b * NH + h) * NN) * 128);
    const char* KKg = (const char*)(KK + ((size_t)(b * NH + h) * NN) * 128);
    const char* Vtg = (const char*)(Vt + ((size_t)(b * NH + h) * 64) * NN);

    // ones B-fragment (bf16 1.0 in all slots) for the row-sum MFMA
    short8 vones;
#pragma unroll
    for (int i = 0; i < 8; i++) vones[i] = (short)0x3F80;

    // prologue: stage full Q tile (32KB) flat into KQs
#pragma unroll
    for (int i = 0; i < 4; i++)
        gload16(QQg + (size_t)n0 * 256 + i * 8192 + w * 1024 + lane * 16,
                (char*)KQs + i * 8192 + w * 1024);
    __syncthreads();
    short8 aq[4];
    {
        int row = w * 16 + lr;   // 0..127
#pragma unroll
        for (int ks = 0; ks < 4; ks++)
            aq[ks] = *reinterpret_cast<const short8*>(
                KQs + row * 128 + (((ks * 4 + lg) ^ (row & 7)) << 3));
    }
    __syncthreads();   // everyone holds Q frags; buffers free

    // stage tile 0 into buf 0
#pragma unroll
    for (int i = 0; i < 2; i++)
        gload16(KKg + i * 8192 + w * 1024 + lane * 16, (char*)KQs + i * 8192 + w * 1024);
    gload16(Vtg + (size_t)(w * 8 + (lane >> 3)) * (NN * 2) + (lane & 7) * 16,
            (char*)Vts + w * 1024);
    __syncthreads();

    f32x4 O[4] = {};
    f32x4 O5 = {};      // row-sum accumulator (l), via ones-MFMA
    float mrun[4];
#pragma unroll
    for (int rg = 0; rg < 4; rg++) mrun[rg] = -1e30f;

    int cur = 0;
    for (int tt = 0; tt < 32; tt++) {
        // issue next-tile stage early (latency hidden under this tile's compute)
        if (tt < 31) {
            int m1 = (tt + 1) * 64;
            int nb = cur ^ 1;
#pragma unroll
            for (int i = 0; i < 2; i++)
                gload16(KKg + (size_t)m1 * 256 + i * 8192 + w * 1024 + lane * 16,
                        (char*)KQs + nb * 16384 + i * 8192 + w * 1024);
            gload16(Vtg + (size_t)(w * 8 + (lane >> 3)) * (NN * 2) + (size_t)m1 * 2 + (lane & 7) * 16,
                    (char*)Vts + nb * 8192 + w * 1024);
        }
        const u16* Kc = KQs + cur * 8192;
        const u16* Vc = Vts + cur * 4096;
        // S = QQ·KK^T  (16 q-rows/wave x 64 kv cols), scale+log2e pre-folded into Q
        f32x4 S[4];
        __builtin_amdgcn_s_setprio(1);
#pragma unroll
        for (int ct = 0; ct < 4; ct++) {
            f32x4 s = {};
#pragma unroll
            for (int ks = 0; ks < 4; ks++) {
                int row = ct * 16 + lr;
                short8 bk = *reinterpret_cast<const short8*>(
                    Kc + row * 128 + (((ks * 4 + lg) ^ (row & 7)) << 3));
                s = __builtin_amdgcn_mfma_f32_16x16x32_bf16(aq[ks], bk, s, 0, 0, 0);
            }
            S[ct] = s;
        }
        __builtin_amdgcn_s_setprio(0);
        // online softmax (exp2 domain), T13 defer-max THR=8:
        // q-row = lg*4+rg, reduce max over lr lanes (kv)
        float mx[4];
#pragma unroll
        for (int rg = 0; rg < 4; rg++) {
            float m0 = fmaxf(fmaxf(S[0][rg], S[1][rg]), fmaxf(S[2][rg], S[3][rg]));
#pragma unroll
            for (int mk = 1; mk < 16; mk <<= 1) m0 = fmaxf(m0, __shfl_xor(m0, mk));
            mx[rg] = m0;
        }
        bool need = (mx[0] > mrun[0] + 8.f) || (mx[1] > mrun[1] + 8.f) ||
                    (mx[2] > mrun[2] + 8.f) || (mx[3] > mrun[3] + 8.f);
        if (__any(need)) {
#pragma unroll
            for (int rg = 0; rg < 4; rg++) {
                float newm = fmaxf(mrun[rg], mx[rg]);
                float sf = exp2f(mrun[rg] - newm);
                mrun[rg] = newm;
#pragma unroll
                for (int dt = 0; dt < 4; dt++) O[dt][rg] *= sf;
                O5[rg] *= sf;
            }
        }
        // P = exp2(S - mrun) -> per-wave LDS strip [16][64] (swizzled)
        u16* Pw = Ps + w * 1024;
#pragma unroll
        for (int ct = 0; ct < 4; ct++) {
            int c = ct * 16 + lr;
#pragma unroll
            for (int rg = 0; rg < 4; rg++) {
                int row = lg * 4 + rg;
                Pw[row * 64 + ((((c >> 3) ^ (row & 7)) << 3) | (c & 7))] =
                    f2bf(exp2f(S[ct][rg] - mrun[rg]));
            }
        }
        short8 pa[2];
#pragma unroll
        for (int ks = 0; ks < 2; ks++)
            pa[ks] = *reinterpret_cast<const short8*>(
                Pw + lr * 64 + (((ks * 4 + lg) ^ (lr & 7)) << 3));
        __builtin_amdgcn_s_setprio(1);
#pragma unroll
        for (int dt = 0; dt < 4; dt++) {
#pragma unroll
            for (int ks = 0; ks < 2; ks++) {
                int vrow = dt * 16 + lr;
                short8 vf = *reinterpret_cast<const short8*>(
                    Vc + vrow * 64 + (((ks * 4 + lg) ^ (vrow & 7)) << 3));
                O[dt] = __builtin_amdgcn_mfma_f32_16x16x32_bf16(pa[ks], vf, O[dt], 0, 0, 0);
            }
        }
        // row-sum: l += P · 1  (2 extra MFMAs on the idle matrix pipe)
#pragma unroll
        for (int ks = 0; ks < 2; ks++)
            O5 = __builtin_amdgcn_mfma_f32_16x16x32_bf16(pa[ks], vones, O5, 0, 0, 0);
        __builtin_amdgcn_s_setprio(0);
        __syncthreads();   // drains next-tile stage (covered) + LDS reads of cur
        cur ^= 1;
    }
    // epilogue: normalize by l=O5, write ctx [B*N][C] bf16 (linear layout)
#pragma unroll
    for (int dt = 0; dt < 4; dt++) {
#pragma unroll
        for (int rg = 0; rg < 4; rg++) {
            int n = n0 + w * 16 + lg * 4 + rg;
            float oo = O[dt][rg] / O5[rg];
            ctx[((size_t)(b * NN) + n) * 1024 + h * 64 + dt * 16 + lr] = f2bf(oo);
        }
    }
}

extern "C" void kernel_launch(void* const* d_in, const int* in_sizes, int n_in,
                              void* d_out, int out_size, void* d_ws, size_t ws_size,
                              hipStream_t stream) {
    const float* x   = (const float*)d_in[0];
    const float* pos = (const float*)d_in[2];
    const float* Wq  = (const float*)d_in[3];
    const float* bq  = (const float*)d_in[4];
    const float* Wk  = (const float*)d_in[5];
    const float* bk  = (const float*)d_in[6];
    const float* Wv  = (const float*)d_in[7];
    const float* bv  = (const float*)d_in[8];
    const float* Wo  = (const float*)d_in[9];
    const float* bo  = (const float*)d_in[10];
    const float* qlw = (const float*)d_in[11];
    const float* qlb = (const float*)d_in[12];
    const float* klw = (const float*)d_in[13];
    const float* klb = (const float*)d_in[14];
    const float* Wp  = (const float*)d_in[15];
    const float* pbu = (const float*)d_in[16];
    const float* pbv = (const float*)d_in[17];
    float* out = (float*)d_out;

    char* ws = (char*)d_ws;
    u16*   xbf   = (u16*)(ws);                      //  8388608 B
    u16*   posbf = (u16*)(ws + 8388608);            //  8388608 B
    u16*   Wbf   = (u16*)(ws + 16777216);           //  5 x 2097152 B (q,k,v,p,o)
    float* pre   = (float*)(ws + 27262976);         //  4 x 16777216 B (q,k,v,p)
    u16*   QQ    = (u16*)(ws + 94371840);           // 16777216 B
    u16*   KK    = (u16*)(ws + 111149056);          // 16777216 B
    u16*   Vt    = (u16*)(ws + 127926272);          //  8388608 B
    u16*   ctx   = (u16*)(ws + 136314880);          //  8388608 B  (total 144703488)

    cast_kernel<<<4096, 256, 0, stream>>>(x, xbf, 1048576);
    cast_kernel<<<4096, 256, 0, stream>>>(pos, posbf, 1048576);
    cast_kernel<<<1024, 256, 0, stream>>>(Wq, Wbf + 0 * 1048576, 262144);
    cast_kernel<<<1024, 256, 0, stream>>>(Wk, Wbf + 1 * 1048576, 262144);
    cast_kernel<<<1024, 256, 0, stream>>>(Wv, Wbf + 2 * 1048576, 262144);
    cast_kernel<<<1024, 256, 0, stream>>>(Wp, Wbf + 3 * 1048576, 262144);
    cast_kernel<<<1024, 256, 0, stream>>>(Wo, Wbf + 4 * 1048576, 262144);

    proj_gemm<<<dim3(8, 32, 4), 256, 0, stream>>>(xbf, posbf, Wbf, pre, bq, bk, bv);
    post_qk<<<dim3(1024, 2), 256, 0, stream>>>(pre, qlw, qlb, klw, klb, pbu, pbv, QQ, KK);
    post_vp<<<dim3(32, 32), 256, 0, stream>>>(pre + (size_t)2 * 4194304, pre + (size_t)3 * 4194304, Vt, KK);
    flash_attn<<<dim3(16, 16, 2), 512, 0, stream>>>(QQ, KK, Vt, ctx);
    out_gemm<<<dim3(8, 32), 256, 0, stream>>>(ctx, Wbf + 4 * 1048576, out, bo);
}

// Round 9
// 241.061 us; speedup vs baseline: 1.3818x; 1.0108x over previous
//
#include <hip/hip_runtime.h>
#include <stdint.h>

// WhaleAttention: B=2 N=2048 C=1024 H=16 D=64
// R9: flash T12-lite: swapped QK^T (S^T in regs, lane owns q-row lr) -> lane-local
// softmax, in-register P->bf16 pack + shfl redistribution to PV A-frags.
// Deletes P LDS strip (LDS 64->48KB) + its bank conflicts + 14 shuffles/tile.

typedef short short8 __attribute__((ext_vector_type(8)));
typedef float f32x4 __attribute__((ext_vector_type(4)));
typedef unsigned short us4 __attribute__((ext_vector_type(4)));
typedef unsigned int u32x4 __attribute__((ext_vector_type(4)));
typedef unsigned short u16;
typedef unsigned int u32;

#define NB 2
#define NN 2048
#define NC 1024
#define NH 16
#define ND 64

__device__ __forceinline__ u16 f2bf(float f) {
    unsigned int u = __float_as_uint(f);
    u += 0x7fffu + ((u >> 16) & 1u);
    return (u16)(u >> 16);
}

// swizzled column for a 128-u16 row: permute 16B chunks by XOR(row&7). involution.
__device__ __forceinline__ int swzc(int row, int c) {
    return (((c >> 3) ^ (row & 7)) << 3) | (c & 7);
}

__device__ __forceinline__ void gload16(const void* g, void* l) {
    __builtin_amdgcn_global_load_lds(
        (const __attribute__((address_space(1))) unsigned int*)g,
        (__attribute__((address_space(3))) unsigned int*)l, 16, 0, 0);
}

// ---------------- cast fp32 -> bf16 ----------------
__global__ __launch_bounds__(256) void cast_kernel(const float* __restrict__ src,
                                                   u16* __restrict__ dst, int n4) {
    int i = blockIdx.x * 256 + threadIdx.x;
    if (i < n4) {
        float4 f = reinterpret_cast<const float4*>(src)[i];
        us4 o;
        o[0] = f2bf(f.x); o[1] = f2bf(f.y); o[2] = f2bf(f.z); o[3] = f2bf(f.w);
        reinterpret_cast<us4*>(dst)[i] = o;
    }
}

// ---------------- GEMM C = A @ W^T (+bias), out fp32; gload_lds + dbuf ----------------
__device__ __forceinline__ void gemm_stage(const u16* __restrict__ A,
                                           const u16* __restrict__ W,
                                           u16* As, u16* Bs,
                                           int m0, int n0, int kk, int w, int lane) {
    int lr4 = lane >> 2, lc8 = (lane & 3) * 8;
#pragma unroll
    for (int i = 0; i < 2; i++) {
        int rbase = w * 32 + i * 16;
        gload16(A + (size_t)(m0 + rbase + lr4) * 1024 + kk + lc8, As + rbase * 32);
        gload16(W + (size_t)(n0 + rbase + lr4) * 1024 + kk + lc8, Bs + rbase * 32);
    }
}

__device__ __forceinline__ void gemm_bt_body(const u16* __restrict__ A,
                                             const u16* __restrict__ W,
                                             float* __restrict__ out,
                                             const float* __restrict__ bias,
                                             int m0, int n0) {
    __shared__ u16 As[2][128 * 32];
    __shared__ u16 Bs[2][128 * 32];
    int t = threadIdx.x, lane = t & 63, w = t >> 6;
    int wm = (w >> 1) * 64, wn = (w & 1) * 64;
    int lr = lane & 15, lg = lane >> 4;
    f32x4 acc[4][4] = {};

    gemm_stage(A, W, As[0], Bs[0], m0, n0, 0, w, lane);
    __syncthreads();
    int cur = 0;
    for (int kt = 0; kt < 32; kt++) {
        if (kt < 31)
            gemm_stage(A, W, As[cur ^ 1], Bs[cur ^ 1], m0, n0, (kt + 1) * 32, w, lane);
        const u16* Ac = As[cur];
        const u16* Bc = Bs[cur];
        short8 af[4], bw[4];
#pragma unroll
        for (int mt = 0; mt < 4; mt++)
            af[mt] = *reinterpret_cast<const short8*>(Ac + (wm + mt * 16 + lr) * 32 + lg * 8);
#pragma unroll
        for (int nt = 0; nt < 4; nt++)
            bw[nt] = *reinterpret_cast<const short8*>(Bc + (wn + nt * 16 + lr) * 32 + lg * 8);
#pragma unroll
        for (int mt = 0; mt < 4; mt++)
#pragma unroll
            for (int nt = 0; nt < 4; nt++)
                acc[mt][nt] = __builtin_amdgcn_mfma_f32_16x16x32_bf16(af[mt], bw[nt], acc[mt][nt], 0, 0, 0);
        __syncthreads();
        cur ^= 1;
    }
#pragma unroll
    for (int mt = 0; mt < 4; mt++) {
#pragma unroll
        for (int nt = 0; nt < 4; nt++) {
            int c = n0 + wn + nt * 16 + lr;
            float badd = bias ? bias[c] : 0.0f;
            int r = m0 + wm + mt * 16 + lg * 4;
#pragma unroll
            for (int rg = 0; rg < 4; rg++)
                out[(size_t)(r + rg) * 1024 + c] = acc[mt][nt][rg] + badd;
        }
    }
}

// z=0:q(bq) 1:k(bk) 2:v(bv) 3:p(none, A=pos)
__global__ __launch_bounds__(256) void proj_gemm(const u16* __restrict__ xbf,
                                                 const u16* __restrict__ posbf,
                                                 const u16* __restrict__ Wbase,
                                                 float* __restrict__ prebase,
                                                 const float* __restrict__ bq,
                                                 const float* __restrict__ bk,
                                                 const float* __restrict__ bv) {
    int z = blockIdx.z;
    const u16* A = (z == 3) ? posbf : xbf;
    const u16* W = Wbase + (size_t)z * 1048576;
    float* out = prebase + (size_t)z * 4194304;
    const float* bias = (z == 0) ? bq : ((z == 1) ? bk : ((z == 2) ? bv : (const float*)nullptr));
    gemm_bt_body(A, W, out, bias, blockIdx.y * 128, blockIdx.x * 128);
}

__global__ __launch_bounds__(256) void out_gemm(const u16* __restrict__ ctx,
                                                const u16* __restrict__ Wo,
                                                float* __restrict__ out,
                                                const float* __restrict__ bo) {
    gemm_bt_body(ctx, Wo, out, bo, blockIdx.y * 128, blockIdx.x * 128);
}

// ---------------- LN on q/k rows; QQ=[s*(q^+u) | s*(q^+v)], KK[:,0:64]=k^  (pre-swizzled)
//   s = 0.125 * log2(e)  (softmax runs in exp2 domain) ----------------
__global__ __launch_bounds__(256) void post_qk(const float* __restrict__ prebase,
                                               const float* __restrict__ qw, const float* __restrict__ qb,
                                               const float* __restrict__ kw, const float* __restrict__ kb,
                                               const float* __restrict__ pbu, const float* __restrict__ pbv,
                                               u16* __restrict__ QQ, u16* __restrict__ KK) {
    const float QSC = 0.125f * 1.44269504089f;
    int isq = (blockIdx.y == 0);
    const float* pre = prebase + (isq ? 0 : (size_t)4194304);
    const float* lw = isq ? qw : kw;
    const float* lb = isq ? qb : kb;
    int wv = threadIdx.x >> 6, lane = threadIdx.x & 63;
    int row = blockIdx.x * 4 + wv;   // 0..4095
    int b = row >> 11, n = row & 2047;
    const float* pr = pre + (size_t)row * 1024;
    float vals[16];
    float s = 0.f, s2 = 0.f;
#pragma unroll
    for (int i = 0; i < 4; i++) {
        float4 f = *reinterpret_cast<const float4*>(pr + i * 256 + lane * 4);
        vals[i * 4 + 0] = f.x; vals[i * 4 + 1] = f.y; vals[i * 4 + 2] = f.z; vals[i * 4 + 3] = f.w;
        s += f.x + f.y + f.z + f.w;
        s2 += f.x * f.x + f.y * f.y + f.z * f.z + f.w * f.w;
    }
#pragma unroll
    for (int m = 1; m < 64; m <<= 1) { s += __shfl_xor(s, m); s2 += __shfl_xor(s2, m); }
    float mean = s * (1.f / 1024.f);
    float var = s2 * (1.f / 1024.f) - mean * mean;
    float inv = rsqrtf(var + 1e-6f);
#pragma unroll
    for (int i = 0; i < 4; i++) {
        int c0 = i * 256 + lane * 4;
        int h = c0 >> 6, d0 = c0 & 63;
        size_t base = ((size_t)(b * NH + h) * NN + n) * 128;
        if (isq) {
            us4 u0, u1;
#pragma unroll
            for (int j = 0; j < 4; j++) {
                float xn = (vals[i * 4 + j] - mean) * inv * lw[c0 + j] + lb[c0 + j];
                u0[j] = f2bf((xn + pbu[h * 64 + d0 + j]) * QSC);
                u1[j] = f2bf((xn + pbv[h * 64 + d0 + j]) * QSC);
            }
            *reinterpret_cast<us4*>(QQ + base + swzc(n, d0)) = u0;
            *reinterpret_cast<us4*>(QQ + base + swzc(n, d0 + 64)) = u1;
        } else {
            us4 u0;
#pragma unroll
            for (int j = 0; j < 4; j++) {
                float xn = (vals[i * 4 + j] - mean) * inv * lw[c0 + j] + lb[c0 + j];
                u0[j] = f2bf(xn);
            }
            *reinterpret_cast<us4*>(KK + base + swzc(n, d0)) = u0;
        }
    }
}

// ---------------- v -> Vt[b][h][d][n] (pre-swizzled: 8-elem chunks in 64-col windows,
//                  key d&7), p -> KK[:,64:128] (pre-swizzled by n) ----------------
__global__ __launch_bounds__(256) void post_vp(const float* __restrict__ vpre,
                                               const float* __restrict__ ppre,
                                               u16* __restrict__ Vt, u16* __restrict__ KK) {
    __shared__ u16 tile[64][66];
    int bh = blockIdx.x;               // 0..31
    int b = bh >> 4, h = bh & 15;
    int n0 = blockIdx.y * 64;
    int t = threadIdx.x, lane = t & 63, w = t >> 6;
#pragma unroll
    for (int j = 0; j < 4; j++) {
        int nr = t >> 2;                 // 0..63
        int d = (t & 3) * 16 + j * 4;    // 0..63
        int n = n0 + nr;
        size_t goff = ((size_t)(b * NN + n)) * 1024 + h * 64 + d;
        float4 fv = *reinterpret_cast<const float4*>(vpre + goff);
        tile[nr][d + 0] = f2bf(fv.x);
        tile[nr][d + 1] = f2bf(fv.y);
        tile[nr][d + 2] = f2bf(fv.z);
        tile[nr][d + 3] = f2bf(fv.w);
        float4 fp = *reinterpret_cast<const float4*>(ppre + goff);
        us4 up; up[0] = f2bf(fp.x); up[1] = f2bf(fp.y); up[2] = f2bf(fp.z); up[3] = f2bf(fp.w);
        *reinterpret_cast<us4*>(KK + ((size_t)(b * NH + h) * NN + n) * 128 + swzc(n, 64 + d)) = up;
    }
    __syncthreads();
    size_t vbase = (size_t)(b * NH + h) * 64 * NN;
    int n = n0 + lane;
#pragma unroll
    for (int j = 0; j < 16; j++) {
        int d = w + j * 4;
        // 64-col window, 8-elem (16B) chunks, XOR key d&7
        int nsw = (n & ~63) | ((((n >> 3) & 7) ^ (d & 7)) << 3) | (n & 7);
        Vt[vbase + (size_t)d * NN + nsw] = tile[lane][d];
    }
}

// ---------------- flash attention: 8 waves x 16 q-rows, KVBLK=64, K/V dbuf,
//                  swapped QK^T + in-register P ----------------
__global__ __launch_bounds__(512, 4) void flash_attn(const u16* __restrict__ QQ,
                                                     const u16* __restrict__ KK,
                                                     const u16* __restrict__ Vt,
                                                     u16* __restrict__ ctx) {
    __shared__ u16 KQs[2 * 64 * 128];   // K dbuf (2x16KB); prologue holds Q 128x128 flat
    __shared__ u16 Vts[2 * 64 * 64];    // V dbuf (2x8KB)   -> total 48KB
    int qt = blockIdx.x, h = blockIdx.y, b = blockIdx.z;
    int n0 = qt * 128;
    int t = threadIdx.x, lane = t & 63, w = t >> 6;   // w: 0..7
    int lr = lane & 15, lg = lane >> 4;
    const char* QQg = (const char*)(QQ + ((size_t)(b * NH + h) * NN) * 128);
    const char* KKg = (const char*)(KK + ((size_t)(b * NH + h) * NN) * 128);
    const char* Vtg = (const char*)(Vt + ((size_t)(b * NH + h) * 64) * NN);

    // ones B-fragment (bf16 1.0) for the row-sum MFMA
    short8 vones;
#pragma unroll
    for (int i = 0; i < 8; i++) vones[i] = (short)0x3F80;

    // prologue: stage full Q tile (32KB) flat into KQs
#pragma unroll
    for (int i = 0; i < 4; i++)
        gload16(QQg + (size_t)n0 * 256 + i * 8192 + w * 1024 + lane * 16,
                (char*)KQs + i * 8192 + w * 1024);
    __syncthreads();
    short8 aq[4];
    {
        int row = w * 16 + lr;   // 0..127
#pragma unroll
        for (int ks = 0; ks < 4; ks++)
            aq[ks] = *reinterpret_cast<const short8*>(
                KQs + row * 128 + (((ks * 4 + lg) ^ (row & 7)) << 3));
    }
    __syncthreads();   // everyone holds Q frags; buffers free

    // stage tile 0 into buf 0
#pragma unroll
    for (int i = 0; i < 2; i++)
        gload16(KKg + i * 8192 + w * 1024 + lane * 16, (char*)KQs + i * 8192 + w * 1024);
    gload16(Vtg + (size_t)(w * 8 + (lane >> 3)) * (NN * 2) + (lane & 7) * 16,
            (char*)Vts + w * 1024);
    __syncthreads();

    f32x4 O[4] = {};
    f32x4 O5 = {};          // row-sum accumulator (l), via ones-MFMA
    float mrun = -1e30f;    // per-lane running max for q-row = w*16 + lr

    int cur = 0;
    for (int tt = 0; tt < 32; tt++) {
        // issue next-tile stage early (latency hidden under this tile's compute)
        if (tt < 31) {
            int m1 = (tt + 1) * 64;
            int nb = cur ^ 1;
#pragma unroll
            for (int i = 0; i < 2; i++)
                gload16(KKg + (size_t)m1 * 256 + i * 8192 + w * 1024 + lane * 16,
                        (char*)KQs + nb * 16384 + i * 8192 + w * 1024);
            gload16(Vtg + (size_t)(w * 8 + (lane >> 3)) * (NN * 2) + (size_t)m1 * 2 + (lane & 7) * 16,
                    (char*)Vts + nb * 8192 + w * 1024);
        }
        const u16* Kc = KQs + cur * 8192;
        const u16* Vc = Vts + cur * 4096;
        // S^T = K·Q^T: lane holds col q=lr, rows kv = ct*16 + 4*lg + rg
        f32x4 S[4];
        __builtin_amdgcn_s_setprio(1);
#pragma unroll
        for (int ct = 0; ct < 4; ct++) {
            f32x4 s = {};
#pragma unroll
            for (int ks = 0; ks < 4; ks++) {
                int row = ct * 16 + lr;
                short8 bk = *reinterpret_cast<const short8*>(
                    Kc + row * 128 + (((ks * 4 + lg) ^ (row & 7)) << 3));
                s = __builtin_amdgcn_mfma_f32_16x16x32_bf16(bk, aq[ks], s, 0, 0, 0);
            }
            S[ct] = s;
        }
        __builtin_amdgcn_s_setprio(0);
        // lane-local max over 16 vals, then reduce across the 4 lane-groups
        float mx = fmaxf(fmaxf(fmaxf(S[0][0], S[0][1]), fmaxf(S[0][2], S[0][3])),
                         fmaxf(fmaxf(S[1][0], S[1][1]), fmaxf(S[1][2], S[1][3])));
        mx = fmaxf(mx, fmaxf(fmaxf(fmaxf(S[2][0], S[2][1]), fmaxf(S[2][2], S[2][3])),
                             fmaxf(fmaxf(S[3][0], S[3][1]), fmaxf(S[3][2], S[3][3]))));
        mx = fmaxf(mx, __shfl_xor(mx, 16));
        mx = fmaxf(mx, __shfl_xor(mx, 32));
        // T13 defer-max THR=8 (exp2 domain)
        if (__any(mx > mrun + 8.f)) {
            float newm = fmaxf(mrun, mx);
            float sf = exp2f(mrun - newm);
            mrun = newm;
            float sfq[4];
#pragma unroll
            for (int rg = 0; rg < 4; rg++)
                sfq[rg] = __shfl(sf, 4 * lg + rg);   // sf of q-row 4*lg+rg (lanes 0..15)
#pragma unroll
            for (int rg = 0; rg < 4; rg++) {
                float s4 = sfq[rg];
#pragma unroll
                for (int dt = 0; dt < 4; dt++) O[dt][rg] *= s4;
                O5[rg] *= s4;
            }
        }
        // P = exp2(S - mrun) -> bf16 pairs in-register: dA[ct]=(rg0,rg1), dB[ct]=(rg2,rg3)
        u32 dA[4], dB[4];
#pragma unroll
        for (int ct = 0; ct < 4; ct++) {
            u16 b0 = f2bf(exp2f(S[ct][0] - mrun));
            u16 b1 = f2bf(exp2f(S[ct][1] - mrun));
            u16 b2 = f2bf(exp2f(S[ct][2] - mrun));
            u16 b3 = f2bf(exp2f(S[ct][3] - mrun));
            dA[ct] = (u32)b0 | ((u32)b1 << 16);
            dB[ct] = (u32)b2 | ((u32)b3 << 16);
        }
        // redistribute to PV A-fragments: pa[ks] needs kv = ks*32 + 8*lg + e
        // X from group 2(lg&1) (e0..3), Y from group 2(lg&1)+1 (e4..7), ct' = 2ks+(lg>>1)
        int lgh = lg >> 1;
        short8 pa[2];
#pragma unroll
        for (int ks = 0; ks < 2; ks++) {
            u32 selfA = lgh ? dA[2 * ks + 1] : dA[2 * ks];
            u32 selfB = lgh ? dB[2 * ks + 1] : dB[2 * ks];
            u32 crossA = lgh ? dA[2 * ks] : dA[2 * ks + 1];
            u32 crossB = lgh ? dB[2 * ks] : dB[2 * ks + 1];
            u32 FA = (u32)__shfl_xor((int)selfA, 16);
            u32 FB = (u32)__shfl_xor((int)selfB, 16);
            u32 EA = (u32)__shfl_xor((int)crossA, 32);
            u32 EB = (u32)__shfl_xor((int)crossB, 32);
            u32 GA = (u32)__shfl_xor((int)EA, 16);
            u32 GB = (u32)__shfl_xor((int)EB, 16);
            u32 XA = (lg == 0) ? selfA : (lg == 1) ? GA : (lg == 2) ? EA : FA;
            u32 XB = (lg == 0) ? selfB : (lg == 1) ? GB : (lg == 2) ? EB : FB;
            u32 YA = (lg == 0) ? FA : (lg == 1) ? EA : (lg == 2) ? GA : selfA;
            u32 YB = (lg == 0) ? FB : (lg == 1) ? EB : (lg == 2) ? GB : selfB;
            u32x4 pv; pv[0] = XA; pv[1] = XB; pv[2] = YA; pv[3] = YB;
            pa[ks] = __builtin_bit_cast(short8, pv);
        }
        // O += P·V ; l += P·1
        __builtin_amdgcn_s_setprio(1);
#pragma unroll
        for (int dt = 0; dt < 4; dt++) {
#pragma unroll
            for (int ks = 0; ks < 2; ks++) {
                int vrow = dt * 16 + lr;
                short8 vf = *reinterpret_cast<const short8*>(
                    Vc + vrow * 64 + (((ks * 4 + lg) ^ (vrow & 7)) << 3));
                O[dt] = __builtin_amdgcn_mfma_f32_16x16x32_bf16(pa[ks], vf, O[dt], 0, 0, 0);
            }
        }
#pragma unroll
        for (int ks = 0; ks < 2; ks++)
            O5 = __builtin_amdgcn_mfma_f32_16x16x32_bf16(pa[ks], vones, O5, 0, 0, 0);
        __builtin_amdgcn_s_setprio(0);
        __syncthreads();   // drains next-tile stage (covered) + LDS reads of cur
        cur ^= 1;
    }
    // epilogue: normalize by l=O5, write ctx [B*N][C] bf16 (linear layout)
#pragma unroll
    for (int dt = 0; dt < 4; dt++) {
#pragma unroll
        for (int rg = 0; rg < 4; rg++) {
            int n = n0 + w * 16 + lg * 4 + rg;
            float oo = O[dt][rg] / O5[rg];
            ctx[((size_t)(b * NN) + n) * 1024 + h * 64 + dt * 16 + lr] = f2bf(oo);
        }
    }
}

extern "C" void kernel_launch(void* const* d_in, const int* in_sizes, int n_in,
                              void* d_out, int out_size, void* d_ws, size_t ws_size,
                              hipStream_t stream) {
    const float* x   = (const float*)d_in[0];
    const float* pos = (const float*)d_in[2];
    const float* Wq  = (const float*)d_in[3];
    const float* bq  = (const float*)d_in[4];
    const float* Wk  = (const float*)d_in[5];
    const float* bk  = (const float*)d_in[6];
    const float* Wv  = (const float*)d_in[7];
    const float* bv  = (const float*)d_in[8];
    const float* Wo  = (const float*)d_in[9];
    const float* bo  = (const float*)d_in[10];
    const float* qlw = (const float*)d_in[11];
    const float* qlb = (const float*)d_in[12];
    const float* klw = (const float*)d_in[13];
    const float* klb = (const float*)d_in[14];
    const float* Wp  = (const float*)d_in[15];
    const float* pbu = (const float*)d_in[16];
    const float* pbv = (const float*)d_in[17];
    float* out = (float*)d_out;

    char* ws = (char*)d_ws;
    u16*   xbf   = (u16*)(ws);                      //  8388608 B
    u16*   posbf = (u16*)(ws + 8388608);            //  8388608 B
    u16*   Wbf   = (u16*)(ws + 16777216);           //  5 x 2097152 B (q,k,v,p,o)
    float* pre   = (float*)(ws + 27262976);         //  4 x 16777216 B (q,k,v,p)
    u16*   QQ    = (u16*)(ws + 94371840);           // 16777216 B
    u16*   KK    = (u16*)(ws + 111149056);          // 16777216 B
    u16*   Vt    = (u16*)(ws + 127926272);          //  8388608 B
    u16*   ctx   = (u16*)(ws + 136314880);          //  8388608 B  (total 144703488)

    cast_kernel<<<4096, 256, 0, stream>>>(x, xbf, 1048576);
    cast_kernel<<<4096, 256, 0, stream>>>(pos, posbf, 1048576);
    cast_kernel<<<1024, 256, 0, stream>>>(Wq, Wbf + 0 * 1048576, 262144);
    cast_kernel<<<1024, 256, 0, stream>>>(Wk, Wbf + 1 * 1048576, 262144);
    cast_kernel<<<1024, 256, 0, stream>>>(Wv, Wbf + 2 * 1048576, 262144);
    cast_kernel<<<1024, 256, 0, stream>>>(Wp, Wbf + 3 * 1048576, 262144);
    cast_kernel<<<1024, 256, 0, stream>>>(Wo, Wbf + 4 * 1048576, 262144);

    proj_gemm<<<dim3(8, 32, 4), 256, 0, stream>>>(xbf, posbf, Wbf, pre, bq, bk, bv);
    post_qk<<<dim3(1024, 2), 256, 0, stream>>>(pre, qlw, qlb, klw, klb, pbu, pbv, QQ, KK);
    post_vp<<<dim3(32, 32), 256, 0, stream>>>(pre + (size_t)2 * 4194304, pre + (size_t)3 * 4194304, Vt, KK);
    flash_attn<<<dim3(16, 16, 2), 512, 0, stream>>>(QQ, KK, Vt, ctx);
    out_gemm<<<dim3(8, 32), 256, 0, stream>>>(ctx, Wbf + 4 * 1048576, out, bo);
}